// Round 25
// baseline (51.318 us; speedup 1.0000x reference)
//
#include <hip/hip_runtime.h>
#include <hip/hip_bf16.h>
#include <stdint.h>

typedef short bh8 __attribute__((ext_vector_type(8)));
typedef short bh4 __attribute__((ext_vector_type(4)));
typedef float fx4 __attribute__((ext_vector_type(4)));

#define B_ 8
#define S_ 2048
#define E_ 1024
#define HD_ 64

__device__ __forceinline__ short f2bf(float f) {
  unsigned u = __builtin_bit_cast(unsigned, f);
  u = u + 0x7FFFu + ((u >> 16) & 1u);   // RNE
  return (short)(u >> 16);
}

#define GL2LDS16(gp, lp) __builtin_amdgcn_global_load_lds( \
    (const __attribute__((address_space(1))) unsigned int*)(gp), \
    (__attribute__((address_space(3))) unsigned int*)(lp), 16, 0, 0)

// Fragment-native layouts (producer = gemm epilogue, consumer = attention):
//   qfr/kfr: [b][t][half][lane][8]  -> elem [t*16 + (lane&15)][half*32 + 8*(lane>>4) + j]
//   vfr:     [b][kt][mm][lane][4]   -> elem V[kt*16 + 4*(lane>>4) + j][16*mm + (lane&15)]

// ---------- cast W (3 x [64][1024] f32) -> wc bf16 [192][1024], order K,Q,V ----------
__global__ __launch_bounds__(256) void castw_k(
    const float* __restrict__ wk, const float* __restrict__ wq,
    const float* __restrict__ wv, short* __restrict__ wc) {
  int i = blockIdx.x * 256 + threadIdx.x;
  int wsel = i >> 13;
  int o = (i & 8191) * 8;
  const float* src = (wsel == 0) ? wk : (wsel == 1) ? wq : wv;
  float4 a = *(const float4*)(src + o);
  float4 b = *(const float4*)(src + o + 4);
  bh8 r = { f2bf(a.x), f2bf(a.y), f2bf(a.z), f2bf(a.w),
            f2bf(b.x), f2bf(b.y), f2bf(b.z), f2bf(b.w) };
  *(bh8*)(wc + wsel * (HD_ * E_) + o) = r;
}

// ---------- QKV GEMM (r22-exact): BM=32, 8 waves, dbuf + counted vmcnt ----------
__global__ __launch_bounds__(512) void qkv_gemm(
    const float* __restrict__ x, const short* __restrict__ wc,
    short* __restrict__ kfr, short* __restrict__ qfr, short* __restrict__ vfr) {
  __shared__ short As[2][32 * 32];
  __shared__ short Bs[2][192 * 32];
  const int tid = threadIdx.x;
  const int w = tid >> 6, l = tid & 63;
  const int c = l & 15, g = l >> 4;
  const int r0 = blockIdx.x * 32;
  const int wr = w & 1, wq = w >> 1;
  const int prow = l >> 2;
  const int pcol = (l & 3) * 8;
  const int at = tid - 256;
  const int ar = at >> 3;
  const int ac = (at & 7) * 4;
  const float* xrow = x + (size_t)(r0 + ar) * E_ + ac;

  fx4 acc[3];
  acc[0] = acc[1] = acc[2] = (fx4){0.f, 0.f, 0.f, 0.f};

  float4 xa;
  if (w < 4) {
    GL2LDS16(wc + (size_t)(16 * w + prow) * E_ + pcol, &Bs[0][w * 512]);
    GL2LDS16(wc + (size_t)(16 * (8 + w) + prow) * E_ + pcol, &Bs[0][(8 + w) * 512]);
  } else {
    GL2LDS16(wc + (size_t)(16 * w + prow) * E_ + pcol, &Bs[0][w * 512]);
    xa = *(const float4*)(xrow);
    bh4 aw = { f2bf(xa.x), f2bf(xa.y), f2bf(xa.z), f2bf(xa.w) };
    *(bh4*)&As[0][ar * 32 + ac] = aw;
    __builtin_amdgcn_sched_barrier(0);
    xa = *(const float4*)(xrow + 32);
  }
  __builtin_amdgcn_sched_barrier(0);
  if (w < 4) { asm volatile("s_waitcnt vmcnt(0) lgkmcnt(0)" ::: "memory"); }
  else       { asm volatile("s_waitcnt vmcnt(1) lgkmcnt(0)" ::: "memory"); }
  __builtin_amdgcn_s_barrier();
  __builtin_amdgcn_sched_barrier(0);

  for (int t = 0; t < 32; ++t) {
    const int cur = t & 1;
    if (t < 31) {
      const int k1 = (t + 1) * 32;
      if (w < 4) {
        GL2LDS16(wc + (size_t)(16 * w + prow) * E_ + k1 + pcol, &Bs[cur ^ 1][w * 512]);
        GL2LDS16(wc + (size_t)(16 * (8 + w) + prow) * E_ + k1 + pcol, &Bs[cur ^ 1][(8 + w) * 512]);
      } else {
        GL2LDS16(wc + (size_t)(16 * w + prow) * E_ + k1 + pcol, &Bs[cur ^ 1][w * 512]);
        bh4 aw = { f2bf(xa.x), f2bf(xa.y), f2bf(xa.z), f2bf(xa.w) };
        *(bh4*)&As[cur ^ 1][ar * 32 + ac] = aw;
        __builtin_amdgcn_sched_barrier(0);
        const int k2 = (t + 2 < 32) ? (t + 2) * 32 : 0;
        xa = *(const float4*)(xrow + k2);
      }
      __builtin_amdgcn_sched_barrier(0);
    }

    bh8 af = *(const bh8*)&As[cur][(16 * wr + c) * 32 + 8 * g];
#pragma unroll
    for (int cc = 0; cc < 3; ++cc) {
      bh8 bf = *(const bh8*)&Bs[cur][(16 * (3 * wq + cc) + c) * 32 + 8 * g];
      acc[cc] = __builtin_amdgcn_mfma_f32_16x16x32_bf16(af, bf, acc[cc], 0, 0, 0);
    }

    if (t < 31) {
      __builtin_amdgcn_sched_barrier(0);
      if (w < 4) { asm volatile("s_waitcnt vmcnt(0) lgkmcnt(0)" ::: "memory"); }
      else       { asm volatile("s_waitcnt vmcnt(1) lgkmcnt(0)" ::: "memory"); }
      __builtin_amdgcn_s_barrier();
      __builtin_amdgcn_sched_barrier(0);
    }
  }

  const int rbase = r0 + 16 * wr + 4 * g;
  const int bb = rbase >> 11;
  const int srw = rbase & (S_ - 1);
  const int kt = srw >> 4;
  const int g2 = (srw & 15) >> 2;
#pragma unroll
  for (int cc = 0; cc < 3; ++cc) {
    const int ctg = 3 * wq + cc;
    const int n = 16 * ctg + c;
    if (ctg < 4) {
      const int h = n >> 5, gg = (n & 31) >> 3, jj = n & 7;
      short* dst = kfr + ((size_t)(((bb * 128 + kt) * 2 + h) * 64 + gg * 16) * 8) + jj;
#pragma unroll
      for (int j = 0; j < 4; ++j)
        dst[(size_t)(((rbase + j) & 15)) * 8] = f2bf(acc[cc][j]);
    } else if (ctg < 8) {
      const int nq = n - 64;
      const int h = nq >> 5, gg = (nq & 31) >> 3, jj = nq & 7;
      short* dst = qfr + ((size_t)(((bb * 128 + kt) * 2 + h) * 64 + gg * 16) * 8) + jj;
#pragma unroll
      for (int j = 0; j < 4; ++j)
        dst[(size_t)(((rbase + j) & 15)) * 8] = f2bf(acc[cc][j] * 0.125f);
    } else {
      const int hd = n - 128;
      const int mm = hd >> 4, c2 = hd & 15;
      bh4 pk = { f2bf(acc[cc][0]), f2bf(acc[cc][1]),
                 f2bf(acc[cc][2]), f2bf(acc[cc][3]) };
      *(bh4*)&vfr[(size_t)(((bb * 128 + kt) * 4 + mm) * 64 + g2 * 16 + c2) * 4] = pk;
    }
  }
}

// ---------- quad-q fused causal flash: 1 block per (b, p<32); q-tiles {2p,2p+1,126-2p,127-2p}
// Each K/V load feeds 4 q-tiles (halves L2 traffic). Fixed-max softmax, 4 linear merges.
__global__ __launch_bounds__(512, 2) void attn_fused5(
    const short* __restrict__ qfr, const short* __restrict__ kfr,
    const short* __restrict__ vfr, float* __restrict__ out) {
  __shared__ float sO[8][16][68];
  __shared__ float sL[8][16];
  const int tid = threadIdx.x;
  const int w = tid >> 6, l = tid & 63;
  const int c = l & 15, g = l >> 4;
  const int b = blockIdx.x >> 5, p = blockIdx.x & 31;
  const int qt0 = 2 * p, qt1 = 2 * p + 1, qt2 = 126 - 2 * p, qt3 = 127 - 2 * p;

  const short* qbB = qfr + (size_t)(b * 128) * 1024;
  const short* kbB = kfr + (size_t)(b * 128) * 1024;
  const short* vbB = vfr + (size_t)(b * 128) * 1024;

  bh8 q0a = *(const bh8*)(qbB + (qt0 * 2 + 0) * 512 + l * 8);
  bh8 q0b = *(const bh8*)(qbB + (qt0 * 2 + 1) * 512 + l * 8);
  bh8 q1a = *(const bh8*)(qbB + (qt1 * 2 + 0) * 512 + l * 8);
  bh8 q1b = *(const bh8*)(qbB + (qt1 * 2 + 1) * 512 + l * 8);
  bh8 q2a = *(const bh8*)(qbB + (qt2 * 2 + 0) * 512 + l * 8);
  bh8 q2b = *(const bh8*)(qbB + (qt2 * 2 + 1) * 512 + l * 8);
  bh8 q3a = *(const bh8*)(qbB + (qt3 * 2 + 0) * 512 + l * 8);
  bh8 q3b = *(const bh8*)(qbB + (qt3 * 2 + 1) * 512 + l * 8);

  fx4 o0[4], o1[4], o2[4], o3[4];
#pragma unroll
  for (int mm = 0; mm < 4; ++mm) {
    o0[mm] = (fx4){0,0,0,0}; o1[mm] = (fx4){0,0,0,0};
    o2[mm] = (fx4){0,0,0,0}; o3[mm] = (fx4){0,0,0,0};
  }
  float l0 = 0.f, l1 = 0.f, l2 = 0.f, l3 = 0.f;

#define QSTEP(QA, QB, OO, LS, QT) \
  if (kt <= (QT)) { \
    fx4 s = {0.f, 0.f, 0.f, 0.f}; \
    s = __builtin_amdgcn_mfma_f32_16x16x32_bf16(kf0, QA, s, 0, 0, 0); \
    s = __builtin_amdgcn_mfma_f32_16x16x32_bf16(kf1, QB, s, 0, 0, 0); \
    if (kt == (QT)) { \
      _Pragma("unroll") \
      for (int j = 0; j < 4; ++j) \
        if (4 * g + j > c) s[j] = -1e30f; \
    } \
    const float e0 = __expf(s[0] - 8.f); \
    const float e1 = __expf(s[1] - 8.f); \
    const float e2 = __expf(s[2] - 8.f); \
    const float e3 = __expf(s[3] - 8.f); \
    LS += (e0 + e1) + (e2 + e3); \
    bh4 pf = { f2bf(e0), f2bf(e1), f2bf(e2), f2bf(e3) }; \
    OO[0] = __builtin_amdgcn_mfma_f32_16x16x16bf16_1k(vf0, pf, OO[0], 0, 0, 0); \
    OO[1] = __builtin_amdgcn_mfma_f32_16x16x16bf16_1k(vf1, pf, OO[1], 0, 0, 0); \
    OO[2] = __builtin_amdgcn_mfma_f32_16x16x16bf16_1k(vf2, pf, OO[2], 0, 0, 0); \
    OO[3] = __builtin_amdgcn_mfma_f32_16x16x16bf16_1k(vf3, pf, OO[3], 0, 0, 0); \
  }

  for (int kt = w; kt <= qt3; kt += 8) {
    const short* kp = kbB + kt * 1024;
    bh8 kf0 = *(const bh8*)(kp + l * 8);
    bh8 kf1 = *(const bh8*)(kp + 512 + l * 8);
    const short* vp = vbB + kt * 1024;
    bh4 vf0 = *(const bh4*)(vp + l * 4);
    bh4 vf1 = *(const bh4*)(vp + 256 + l * 4);
    bh4 vf2 = *(const bh4*)(vp + 512 + l * 4);
    bh4 vf3 = *(const bh4*)(vp + 768 + l * 4);

    QSTEP(q3a, q3b, o3, l3, qt3)            // always active (kt <= qt3)
    QSTEP(q2a, q2b, o2, l2, qt2)            // all but kt == qt3
    QSTEP(q1a, q1b, o1, l1, qt1)            // wave-uniform conditions
    QSTEP(q0a, q0b, o0, l0, qt0)
  }
#undef QSTEP

#define MERGE(OO, LS, QT) \
  { \
    _Pragma("unroll") \
    for (int mm = 0; mm < 4; ++mm) \
      *(fx4*)&sO[w][c][16 * mm + 4 * g] = OO[mm]; \
    LS += __shfl_xor(LS, 16, 64); \
    LS += __shfl_xor(LS, 32, 64); \
    if (g == 0) sL[w][c] = LS; \
    __syncthreads(); \
    if (w < 4) { \
      const int r = tid >> 4; \
      const int cg4 = (tid & 15) * 4; \
      fx4 a = {0.f, 0.f, 0.f, 0.f}; \
      float L = 0.f; \
      _Pragma("unroll") \
      for (int i = 0; i < 8; ++i) { a += *(const fx4*)&sO[i][r][cg4]; L += sL[i][r]; } \
      fx4 res = a * (1.0f / L); \
      *(fx4*)(out + ((size_t)(b * S_ + (QT) * 16 + r)) * HD_ + cg4) = res; \
    } \
    __syncthreads(); \
  }

  MERGE(o0, l0, qt0)
  MERGE(o1, l1, qt1)
  MERGE(o2, l2, qt2)
  MERGE(o3, l3, qt3)
#undef MERGE
}

extern "C" void kernel_launch(void* const* d_in, const int* in_sizes, int n_in,
                              void* d_out, int out_size, void* d_ws, size_t ws_size,
                              hipStream_t stream) {
  const float* x  = (const float*)d_in[0];
  const float* wk = (const float*)d_in[1];
  const float* wq = (const float*)d_in[2];
  const float* wv = (const float*)d_in[3];
  float* out = (float*)d_out;
  char* ws = (char*)d_ws;
  short* wc  = (short*)(ws);                         // 384 KB
  short* kfr = (short*)(ws + 393216);                // 2 MB
  short* qfr = (short*)(ws + 2490368);               // 2 MB
  short* vfr = (short*)(ws + 4587520);               // 2 MB (total 6.5 MB)

  castw_k<<<dim3(96), dim3(256), 0, stream>>>(wk, wq, wv, wc);
  qkv_gemm<<<dim3(512), dim3(512), 0, stream>>>(x, wc, kfr, qfr, vfr);
  attn_fused5<<<dim3(256), dim3(512), 0, stream>>>(qfr, kfr, vfr, out);
}

// Round 26
// 45.468 us; speedup vs baseline: 1.1287x; 1.1287x over previous
//
#include <hip/hip_runtime.h>
#include <hip/hip_bf16.h>
#include <stdint.h>

typedef short bh8 __attribute__((ext_vector_type(8)));
typedef short bh4 __attribute__((ext_vector_type(4)));
typedef float fx4 __attribute__((ext_vector_type(4)));

#define B_ 8
#define S_ 2048
#define E_ 1024
#define HD_ 64

__device__ __forceinline__ short f2bf(float f) {
  unsigned u = __builtin_bit_cast(unsigned, f);
  u = u + 0x7FFFu + ((u >> 16) & 1u);   // RNE
  return (short)(u >> 16);
}

#define GL2LDS16(gp, lp) __builtin_amdgcn_global_load_lds( \
    (const __attribute__((address_space(1))) unsigned int*)(gp), \
    (__attribute__((address_space(3))) unsigned int*)(lp), 16, 0, 0)

// Fragment-native layouts (producer = gemm epilogue, consumer = attention):
//   qfr/kfr: [b][t][half][lane][8]  -> elem [t*16 + (lane&15)][half*32 + 8*(lane>>4) + j]
//   vfr:     [b][kt][mm][lane][4]   -> elem V[kt*16 + 4*(lane>>4) + j][16*mm + (lane&15)]

// ---------- cast W (3 x [64][1024] f32) -> wc bf16 [192][1024], order K,Q,V ----------
__global__ __launch_bounds__(256) void castw_k(
    const float* __restrict__ wk, const float* __restrict__ wq,
    const float* __restrict__ wv, short* __restrict__ wc) {
  int i = blockIdx.x * 256 + threadIdx.x;
  int wsel = i >> 13;
  int o = (i & 8191) * 8;
  const float* src = (wsel == 0) ? wk : (wsel == 1) ? wq : wv;
  float4 a = *(const float4*)(src + o);
  float4 b = *(const float4*)(src + o + 4);
  bh8 r = { f2bf(a.x), f2bf(a.y), f2bf(a.z), f2bf(a.w),
            f2bf(b.x), f2bf(b.y), f2bf(b.z), f2bf(b.w) };
  *(bh8*)(wc + wsel * (HD_ * E_) + o) = r;
}

// ---------- QKV GEMM: BM=64 (halves wc re-read traffic), 8 waves, dbuf + counted vmcnt --
// grid 256. Wave (wr=w&3 row-quarter, wq=w>>2 col-half): 16 rows x 96 cols, 6 MFMA/step.
// Waves 0-3: 3 B-plane glds each (vmcnt 0). Waves 4-7: A-quarter via reg-held x (vmcnt 2).
__global__ __launch_bounds__(512) void qkv_gemm(
    const float* __restrict__ x, const short* __restrict__ wc,
    short* __restrict__ kfr, short* __restrict__ qfr, short* __restrict__ vfr) {
  __shared__ short As[2][64 * 32];     // 2 x 4 KB
  __shared__ short Bs[2][192 * 32];    // 2 x 12 KB
  const int tid = threadIdx.x;
  const int w = tid >> 6, l = tid & 63;
  const int c = l & 15, g = l >> 4;
  const int r0 = blockIdx.x * 64;
  const int wr = w & 3, wq = w >> 2;
  const int prow = l >> 2;             // B-plane staging row (0..15)
  const int pcol = (l & 3) * 8;        // 16B/lane
  const int at = tid - 256;            // A staging (waves 4-7)
  const int arow = at >> 2;            // 0..63
  const int acol = (at & 3) * 8;       // 0,8,16,24
  const float* xrow = x + (size_t)(r0 + arow) * E_ + acol;

  fx4 acc[6];
#pragma unroll
  for (int cc = 0; cc < 6; ++cc) acc[cc] = (fx4){0.f, 0.f, 0.f, 0.f};

  float4 xa0, xa1;
  // prologue: stage tile 0 into buf 0; x(1) left in flight for waves 4-7
  if (w < 4) {
    GL2LDS16(wc + (size_t)(16 * w + prow) * E_ + pcol, &Bs[0][w * 512]);
    GL2LDS16(wc + (size_t)(16 * (4 + w) + prow) * E_ + pcol, &Bs[0][(4 + w) * 512]);
    GL2LDS16(wc + (size_t)(16 * (8 + w) + prow) * E_ + pcol, &Bs[0][(8 + w) * 512]);
  } else {
    xa0 = *(const float4*)(xrow);
    xa1 = *(const float4*)(xrow + 4);
    bh8 aw = { f2bf(xa0.x), f2bf(xa0.y), f2bf(xa0.z), f2bf(xa0.w),
               f2bf(xa1.x), f2bf(xa1.y), f2bf(xa1.z), f2bf(xa1.w) };
    *(bh8*)&As[0][arow * 32 + acol] = aw;
    __builtin_amdgcn_sched_barrier(0);
    xa0 = *(const float4*)(xrow + 32);           // x(1), stays in flight
    xa1 = *(const float4*)(xrow + 32 + 4);
  }
  __builtin_amdgcn_sched_barrier(0);
  if (w < 4) { asm volatile("s_waitcnt vmcnt(0) lgkmcnt(0)" ::: "memory"); }
  else       { asm volatile("s_waitcnt vmcnt(2) lgkmcnt(0)" ::: "memory"); }
  __builtin_amdgcn_s_barrier();
  __builtin_amdgcn_sched_barrier(0);

  for (int t = 0; t < 32; ++t) {
    const int cur = t & 1;
    if (t < 31) {
      const int k1 = (t + 1) * 32;
      if (w < 4) {
        GL2LDS16(wc + (size_t)(16 * w + prow) * E_ + k1 + pcol, &Bs[cur ^ 1][w * 512]);
        GL2LDS16(wc + (size_t)(16 * (4 + w) + prow) * E_ + k1 + pcol, &Bs[cur ^ 1][(4 + w) * 512]);
        GL2LDS16(wc + (size_t)(16 * (8 + w) + prow) * E_ + k1 + pcol, &Bs[cur ^ 1][(8 + w) * 512]);
      } else {
        bh8 aw = { f2bf(xa0.x), f2bf(xa0.y), f2bf(xa0.z), f2bf(xa0.w),
                   f2bf(xa1.x), f2bf(xa1.y), f2bf(xa1.z), f2bf(xa1.w) };  // waits xa(t+1)
        *(bh8*)&As[cur ^ 1][arow * 32 + acol] = aw;
        __builtin_amdgcn_sched_barrier(0);       // pin: x(t+2) issued AFTER the ds_write
        const int k2 = (t + 2 < 32) ? (t + 2) * 32 : 0;
        xa0 = *(const float4*)(xrow + k2);
        xa1 = *(const float4*)(xrow + k2 + 4);
      }
      __builtin_amdgcn_sched_barrier(0);
    }

    // compute tile t (overlaps glds(t+1) + x(t+2) flight)
    bh8 af = *(const bh8*)&As[cur][(16 * wr + c) * 32 + 8 * g];
#pragma unroll
    for (int cc = 0; cc < 6; ++cc) {
      bh8 bf = *(const bh8*)&Bs[cur][(16 * (6 * wq + cc) + c) * 32 + 8 * g];
      acc[cc] = __builtin_amdgcn_mfma_f32_16x16x32_bf16(af, bf, acc[cc], 0, 0, 0);
    }

    if (t < 31) {
      __builtin_amdgcn_sched_barrier(0);
      if (w < 4) { asm volatile("s_waitcnt vmcnt(0) lgkmcnt(0)" ::: "memory"); }
      else       { asm volatile("s_waitcnt vmcnt(2) lgkmcnt(0)" ::: "memory"); }
      __builtin_amdgcn_s_barrier();
      __builtin_amdgcn_sched_barrier(0);
    }
  }

  // epilogue: element OUT[rbase+j][n] -> fragment-native layouts (r20-proven 6-frag map)
  const int rbase = r0 + 16 * wr + 4 * g;
  const int bb = rbase >> 11;
  const int srw = rbase & (S_ - 1);
  const int kt = srw >> 4;
  const int g2 = (srw & 15) >> 2;
#pragma unroll
  for (int cc = 0; cc < 6; ++cc) {
    const int ctg = 6 * wq + cc;
    const int n = 16 * ctg + c;
    if (ctg < 4) {                         // K element [rbase+j][n]
      const int h = n >> 5, gg = (n & 31) >> 3, jj = n & 7;
      short* dst = kfr + ((size_t)(((bb * 128 + kt) * 2 + h) * 64 + gg * 16) * 8) + jj;
#pragma unroll
      for (int j = 0; j < 4; ++j)
        dst[(size_t)(((rbase + j) & 15)) * 8] = f2bf(acc[cc][j]);
    } else if (ctg < 8) {                  // Q (pre-scaled 1/8)
      const int nq = n - 64;
      const int h = nq >> 5, gg = (nq & 31) >> 3, jj = nq & 7;
      short* dst = qfr + ((size_t)(((bb * 128 + kt) * 2 + h) * 64 + gg * 16) * 8) + jj;
#pragma unroll
      for (int j = 0; j < 4; ++j)
        dst[(size_t)(((rbase + j) & 15)) * 8] = f2bf(acc[cc][j] * 0.125f);
    } else {                               // V element V[rbase+j][hd]
      const int hd = n - 128;
      const int mm = hd >> 4, c2 = hd & 15;
      bh4 pk = { f2bf(acc[cc][0]), f2bf(acc[cc][1]),
                 f2bf(acc[cc][2]), f2bf(acc[cc][3]) };
      *(bh4*)&vfr[(size_t)(((bb * 128 + kt) * 4 + mm) * 64 + g2 * 16 + c2) * 4] = pk;
    }
  }
}

// ---------- fused dual-q causal flash (r22-exact): strided k-tiles, shared K/V ----------
__global__ __launch_bounds__(512, 4) void attn_fused3(
    const short* __restrict__ qfr, const short* __restrict__ kfr,
    const short* __restrict__ vfr, float* __restrict__ out) {
  __shared__ float sO[8][16][68];
  __shared__ float sL[8][16];
  const int tid = threadIdx.x;
  const int w = tid >> 6, l = tid & 63;
  const int c = l & 15, g = l >> 4;
  const int b = blockIdx.x >> 6, p = blockIdx.x & 63;
  const int qtA = p, qtB = 127 - p;

  const short* qbB = qfr + (size_t)(b * 128) * 1024;
  const short* kbB = kfr + (size_t)(b * 128) * 1024;
  const short* vbB = vfr + (size_t)(b * 128) * 1024;

  bh8 qA0 = *(const bh8*)(qbB + (qtA * 2 + 0) * 512 + l * 8);
  bh8 qA1 = *(const bh8*)(qbB + (qtA * 2 + 1) * 512 + l * 8);
  bh8 qB0 = *(const bh8*)(qbB + (qtB * 2 + 0) * 512 + l * 8);
  bh8 qB1 = *(const bh8*)(qbB + (qtB * 2 + 1) * 512 + l * 8);

  fx4 oA[4], oB[4];
#pragma unroll
  for (int mm = 0; mm < 4; ++mm) { oA[mm] = (fx4){0,0,0,0}; oB[mm] = (fx4){0,0,0,0}; }
  float lA = 0.f, lB = 0.f;

  for (int kt = w; kt <= qtB; kt += 8) {
    const short* kp = kbB + kt * 1024;
    bh8 kf0 = *(const bh8*)(kp + l * 8);
    bh8 kf1 = *(const bh8*)(kp + 512 + l * 8);
    const short* vp = vbB + kt * 1024;
    bh4 vf0 = *(const bh4*)(vp + l * 4);
    bh4 vf1 = *(const bh4*)(vp + 256 + l * 4);
    bh4 vf2 = *(const bh4*)(vp + 512 + l * 4);
    bh4 vf3 = *(const bh4*)(vp + 768 + l * 4);

    fx4 sB = {0.f, 0.f, 0.f, 0.f};
    sB = __builtin_amdgcn_mfma_f32_16x16x32_bf16(kf0, qB0, sB, 0, 0, 0);
    sB = __builtin_amdgcn_mfma_f32_16x16x32_bf16(kf1, qB1, sB, 0, 0, 0);
    if (kt == qtB) {
#pragma unroll
      for (int j = 0; j < 4; ++j)
        if (4 * g + j > c) sB[j] = -1e30f;
    }
    const float pB0 = __expf(sB[0] - 8.f);
    const float pB1 = __expf(sB[1] - 8.f);
    const float pB2 = __expf(sB[2] - 8.f);
    const float pB3 = __expf(sB[3] - 8.f);
    lB += (pB0 + pB1) + (pB2 + pB3);
    bh4 pfB = { f2bf(pB0), f2bf(pB1), f2bf(pB2), f2bf(pB3) };
    oB[0] = __builtin_amdgcn_mfma_f32_16x16x16bf16_1k(vf0, pfB, oB[0], 0, 0, 0);
    oB[1] = __builtin_amdgcn_mfma_f32_16x16x16bf16_1k(vf1, pfB, oB[1], 0, 0, 0);
    oB[2] = __builtin_amdgcn_mfma_f32_16x16x16bf16_1k(vf2, pfB, oB[2], 0, 0, 0);
    oB[3] = __builtin_amdgcn_mfma_f32_16x16x16bf16_1k(vf3, pfB, oB[3], 0, 0, 0);

    if (kt <= qtA) {                          // wave-uniform
      fx4 sA = {0.f, 0.f, 0.f, 0.f};
      sA = __builtin_amdgcn_mfma_f32_16x16x32_bf16(kf0, qA0, sA, 0, 0, 0);
      sA = __builtin_amdgcn_mfma_f32_16x16x32_bf16(kf1, qA1, sA, 0, 0, 0);
      if (kt == qtA) {
#pragma unroll
        for (int j = 0; j < 4; ++j)
          if (4 * g + j > c) sA[j] = -1e30f;
      }
      const float pA0 = __expf(sA[0] - 8.f);
      const float pA1 = __expf(sA[1] - 8.f);
      const float pA2 = __expf(sA[2] - 8.f);
      const float pA3 = __expf(sA[3] - 8.f);
      lA += (pA0 + pA1) + (pA2 + pA3);
      bh4 pfA = { f2bf(pA0), f2bf(pA1), f2bf(pA2), f2bf(pA3) };
      oA[0] = __builtin_amdgcn_mfma_f32_16x16x16bf16_1k(vf0, pfA, oA[0], 0, 0, 0);
      oA[1] = __builtin_amdgcn_mfma_f32_16x16x16bf16_1k(vf1, pfA, oA[1], 0, 0, 0);
      oA[2] = __builtin_amdgcn_mfma_f32_16x16x16bf16_1k(vf2, pfA, oA[2], 0, 0, 0);
      oA[3] = __builtin_amdgcn_mfma_f32_16x16x16bf16_1k(vf3, pfA, oA[3], 0, 0, 0);
    }
  }

  // ---- merge A (linear sum), then merge B, reusing sO/sL ----
#pragma unroll
  for (int mm = 0; mm < 4; ++mm)
    *(fx4*)&sO[w][c][16 * mm + 4 * g] = oA[mm];
  lA += __shfl_xor(lA, 16, 64);
  lA += __shfl_xor(lA, 32, 64);
  if (g == 0) sL[w][c] = lA;
  __syncthreads();
  if (w < 4) {
    const int r = tid >> 4;
    const int cg4 = (tid & 15) * 4;
    fx4 a = {0.f, 0.f, 0.f, 0.f};
    float L = 0.f;
#pragma unroll
    for (int i = 0; i < 8; ++i) { a += *(const fx4*)&sO[i][r][cg4]; L += sL[i][r]; }
    fx4 res = a * (1.0f / L);
    *(fx4*)(out + ((size_t)(b * S_ + qtA * 16 + r)) * HD_ + cg4) = res;
  }
  __syncthreads();
#pragma unroll
  for (int mm = 0; mm < 4; ++mm)
    *(fx4*)&sO[w][c][16 * mm + 4 * g] = oB[mm];
  lB += __shfl_xor(lB, 16, 64);
  lB += __shfl_xor(lB, 32, 64);
  if (g == 0) sL[w][c] = lB;
  __syncthreads();
  if (w < 4) {
    const int r = tid >> 4;
    const int cg4 = (tid & 15) * 4;
    fx4 a = {0.f, 0.f, 0.f, 0.f};
    float L = 0.f;
#pragma unroll
    for (int i = 0; i < 8; ++i) { a += *(const fx4*)&sO[i][r][cg4]; L += sL[i][r]; }
    fx4 res = a * (1.0f / L);
    *(fx4*)(out + ((size_t)(b * S_ + qtB * 16 + r)) * HD_ + cg4) = res;
  }
}

extern "C" void kernel_launch(void* const* d_in, const int* in_sizes, int n_in,
                              void* d_out, int out_size, void* d_ws, size_t ws_size,
                              hipStream_t stream) {
  const float* x  = (const float*)d_in[0];
  const float* wk = (const float*)d_in[1];
  const float* wq = (const float*)d_in[2];
  const float* wv = (const float*)d_in[3];
  float* out = (float*)d_out;
  char* ws = (char*)d_ws;
  short* wc  = (short*)(ws);                         // 384 KB
  short* kfr = (short*)(ws + 393216);                // 2 MB
  short* qfr = (short*)(ws + 2490368);               // 2 MB
  short* vfr = (short*)(ws + 4587520);               // 2 MB (total 6.5 MB)

  castw_k<<<dim3(96), dim3(256), 0, stream>>>(wk, wq, wv, wc);
  qkv_gemm<<<dim3(256), dim3(512), 0, stream>>>(x, wc, kfr, qfr, vfr);
  attn_fused3<<<dim3(512), dim3(512), 0, stream>>>(qfr, kfr, vfr, out);
}

// Round 27
// 43.239 us; speedup vs baseline: 1.1868x; 1.0515x over previous
//
#include <hip/hip_runtime.h>
#include <hip/hip_bf16.h>
#include <stdint.h>

typedef short bh8 __attribute__((ext_vector_type(8)));
typedef short bh4 __attribute__((ext_vector_type(4)));
typedef float fx4 __attribute__((ext_vector_type(4)));

#define B_ 8
#define S_ 2048
#define E_ 1024
#define HD_ 64

__device__ __forceinline__ short f2bf(float f) {
  unsigned u = __builtin_bit_cast(unsigned, f);
  u = u + 0x7FFFu + ((u >> 16) & 1u);   // RNE
  return (short)(u >> 16);
}

#define GL2LDS16(gp, lp) __builtin_amdgcn_global_load_lds( \
    (const __attribute__((address_space(1))) unsigned int*)(gp), \
    (__attribute__((address_space(3))) unsigned int*)(lp), 16, 0, 0)

// Fragment-native layouts (producer = gemm epilogue, consumer = attention):
//   qfr/kfr: [b][t][half][lane][8]  -> elem [t*16 + (lane&15)][half*32 + 8*(lane>>4) + j]
//   vfr:     [b][kt][mm][lane][4]   -> elem V[kt*16 + 4*(lane>>4) + j][16*mm + (lane&15)]

// ---------- cast W (3 x [64][1024] f32) -> wc bf16 [192][1024], order K,Q,V ----------
__global__ __launch_bounds__(256) void castw_k(
    const float* __restrict__ wk, const float* __restrict__ wq,
    const float* __restrict__ wv, short* __restrict__ wc) {
  int i = blockIdx.x * 256 + threadIdx.x;
  int wsel = i >> 13;
  int o = (i & 8191) * 8;
  const float* src = (wsel == 0) ? wk : (wsel == 1) ? wq : wv;
  float4 a = *(const float4*)(src + o);
  float4 b = *(const float4*)(src + o + 4);
  bh8 r = { f2bf(a.x), f2bf(a.y), f2bf(a.z), f2bf(a.w),
            f2bf(b.x), f2bf(b.y), f2bf(b.z), f2bf(b.w) };
  *(bh8*)(wc + wsel * (HD_ * E_) + o) = r;
}

// ---------- QKV GEMM (r26-exact): BM=64, 8 waves, dbuf + counted vmcnt ----------
__global__ __launch_bounds__(512) void qkv_gemm(
    const float* __restrict__ x, const short* __restrict__ wc,
    short* __restrict__ kfr, short* __restrict__ qfr, short* __restrict__ vfr) {
  __shared__ short As[2][64 * 32];     // 2 x 4 KB
  __shared__ short Bs[2][192 * 32];    // 2 x 12 KB
  const int tid = threadIdx.x;
  const int w = tid >> 6, l = tid & 63;
  const int c = l & 15, g = l >> 4;
  const int r0 = blockIdx.x * 64;
  const int wr = w & 3, wq = w >> 2;
  const int prow = l >> 2;             // B-plane staging row (0..15)
  const int pcol = (l & 3) * 8;        // 16B/lane
  const int at = tid - 256;            // A staging (waves 4-7)
  const int arow = at >> 2;            // 0..63
  const int acol = (at & 3) * 8;       // 0,8,16,24
  const float* xrow = x + (size_t)(r0 + arow) * E_ + acol;

  fx4 acc[6];
#pragma unroll
  for (int cc = 0; cc < 6; ++cc) acc[cc] = (fx4){0.f, 0.f, 0.f, 0.f};

  float4 xa0, xa1;
  if (w < 4) {
    GL2LDS16(wc + (size_t)(16 * w + prow) * E_ + pcol, &Bs[0][w * 512]);
    GL2LDS16(wc + (size_t)(16 * (4 + w) + prow) * E_ + pcol, &Bs[0][(4 + w) * 512]);
    GL2LDS16(wc + (size_t)(16 * (8 + w) + prow) * E_ + pcol, &Bs[0][(8 + w) * 512]);
  } else {
    xa0 = *(const float4*)(xrow);
    xa1 = *(const float4*)(xrow + 4);
    bh8 aw = { f2bf(xa0.x), f2bf(xa0.y), f2bf(xa0.z), f2bf(xa0.w),
               f2bf(xa1.x), f2bf(xa1.y), f2bf(xa1.z), f2bf(xa1.w) };
    *(bh8*)&As[0][arow * 32 + acol] = aw;
    __builtin_amdgcn_sched_barrier(0);
    xa0 = *(const float4*)(xrow + 32);
    xa1 = *(const float4*)(xrow + 32 + 4);
  }
  __builtin_amdgcn_sched_barrier(0);
  if (w < 4) { asm volatile("s_waitcnt vmcnt(0) lgkmcnt(0)" ::: "memory"); }
  else       { asm volatile("s_waitcnt vmcnt(2) lgkmcnt(0)" ::: "memory"); }
  __builtin_amdgcn_s_barrier();
  __builtin_amdgcn_sched_barrier(0);

  for (int t = 0; t < 32; ++t) {
    const int cur = t & 1;
    if (t < 31) {
      const int k1 = (t + 1) * 32;
      if (w < 4) {
        GL2LDS16(wc + (size_t)(16 * w + prow) * E_ + k1 + pcol, &Bs[cur ^ 1][w * 512]);
        GL2LDS16(wc + (size_t)(16 * (4 + w) + prow) * E_ + k1 + pcol, &Bs[cur ^ 1][(4 + w) * 512]);
        GL2LDS16(wc + (size_t)(16 * (8 + w) + prow) * E_ + k1 + pcol, &Bs[cur ^ 1][(8 + w) * 512]);
      } else {
        bh8 aw = { f2bf(xa0.x), f2bf(xa0.y), f2bf(xa0.z), f2bf(xa0.w),
                   f2bf(xa1.x), f2bf(xa1.y), f2bf(xa1.z), f2bf(xa1.w) };
        *(bh8*)&As[cur ^ 1][arow * 32 + acol] = aw;
        __builtin_amdgcn_sched_barrier(0);
        const int k2 = (t + 2 < 32) ? (t + 2) * 32 : 0;
        xa0 = *(const float4*)(xrow + k2);
        xa1 = *(const float4*)(xrow + k2 + 4);
      }
      __builtin_amdgcn_sched_barrier(0);
    }

    bh8 af = *(const bh8*)&As[cur][(16 * wr + c) * 32 + 8 * g];
#pragma unroll
    for (int cc = 0; cc < 6; ++cc) {
      bh8 bf = *(const bh8*)&Bs[cur][(16 * (6 * wq + cc) + c) * 32 + 8 * g];
      acc[cc] = __builtin_amdgcn_mfma_f32_16x16x32_bf16(af, bf, acc[cc], 0, 0, 0);
    }

    if (t < 31) {
      __builtin_amdgcn_sched_barrier(0);
      if (w < 4) { asm volatile("s_waitcnt vmcnt(0) lgkmcnt(0)" ::: "memory"); }
      else       { asm volatile("s_waitcnt vmcnt(2) lgkmcnt(0)" ::: "memory"); }
      __builtin_amdgcn_s_barrier();
      __builtin_amdgcn_sched_barrier(0);
    }
  }

  const int rbase = r0 + 16 * wr + 4 * g;
  const int bb = rbase >> 11;
  const int srw = rbase & (S_ - 1);
  const int kt = srw >> 4;
  const int g2 = (srw & 15) >> 2;
#pragma unroll
  for (int cc = 0; cc < 6; ++cc) {
    const int ctg = 6 * wq + cc;
    const int n = 16 * ctg + c;
    if (ctg < 4) {
      const int h = n >> 5, gg = (n & 31) >> 3, jj = n & 7;
      short* dst = kfr + ((size_t)(((bb * 128 + kt) * 2 + h) * 64 + gg * 16) * 8) + jj;
#pragma unroll
      for (int j = 0; j < 4; ++j)
        dst[(size_t)(((rbase + j) & 15)) * 8] = f2bf(acc[cc][j]);
    } else if (ctg < 8) {
      const int nq = n - 64;
      const int h = nq >> 5, gg = (nq & 31) >> 3, jj = nq & 7;
      short* dst = qfr + ((size_t)(((bb * 128 + kt) * 2 + h) * 64 + gg * 16) * 8) + jj;
#pragma unroll
      for (int j = 0; j < 4; ++j)
        dst[(size_t)(((rbase + j) & 15)) * 8] = f2bf(acc[cc][j] * 0.125f);
    } else {
      const int hd = n - 128;
      const int mm = hd >> 4, c2 = hd & 15;
      bh4 pk = { f2bf(acc[cc][0]), f2bf(acc[cc][1]),
                 f2bf(acc[cc][2]), f2bf(acc[cc][3]) };
      *(bh4*)&vfr[(size_t)(((bb * 128 + kt) * 4 + mm) * 64 + g2 * 16 + c2) * 4] = pk;
    }
  }
}

// ---------- fused dual-q causal flash with XCD-aware batch mapping ----------
// Dispatch round-robins XCD = blk % 8; decode b = blk & 7 so all 64 blocks of a batch
// land on one XCD -> per-XCD K/V working set = 2 MB, fits the 4 MB L2 (no thrash).
__global__ __launch_bounds__(512, 4) void attn_fused3(
    const short* __restrict__ qfr, const short* __restrict__ kfr,
    const short* __restrict__ vfr, float* __restrict__ out) {
  __shared__ float sO[8][16][68];
  __shared__ float sL[8][16];
  const int tid = threadIdx.x;
  const int w = tid >> 6, l = tid & 63;
  const int c = l & 15, g = l >> 4;
  const int b = blockIdx.x & 7, p = blockIdx.x >> 3;   // XCD-aware: batch = blk % 8
  const int qtA = p, qtB = 127 - p;

  const short* qbB = qfr + (size_t)(b * 128) * 1024;
  const short* kbB = kfr + (size_t)(b * 128) * 1024;
  const short* vbB = vfr + (size_t)(b * 128) * 1024;

  bh8 qA0 = *(const bh8*)(qbB + (qtA * 2 + 0) * 512 + l * 8);
  bh8 qA1 = *(const bh8*)(qbB + (qtA * 2 + 1) * 512 + l * 8);
  bh8 qB0 = *(const bh8*)(qbB + (qtB * 2 + 0) * 512 + l * 8);
  bh8 qB1 = *(const bh8*)(qbB + (qtB * 2 + 1) * 512 + l * 8);

  fx4 oA[4], oB[4];
#pragma unroll
  for (int mm = 0; mm < 4; ++mm) { oA[mm] = (fx4){0,0,0,0}; oB[mm] = (fx4){0,0,0,0}; }
  float lA = 0.f, lB = 0.f;

  for (int kt = w; kt <= qtB; kt += 8) {
    const short* kp = kbB + kt * 1024;
    bh8 kf0 = *(const bh8*)(kp + l * 8);
    bh8 kf1 = *(const bh8*)(kp + 512 + l * 8);
    const short* vp = vbB + kt * 1024;
    bh4 vf0 = *(const bh4*)(vp + l * 4);
    bh4 vf1 = *(const bh4*)(vp + 256 + l * 4);
    bh4 vf2 = *(const bh4*)(vp + 512 + l * 4);
    bh4 vf3 = *(const bh4*)(vp + 768 + l * 4);

    fx4 sB = {0.f, 0.f, 0.f, 0.f};
    sB = __builtin_amdgcn_mfma_f32_16x16x32_bf16(kf0, qB0, sB, 0, 0, 0);
    sB = __builtin_amdgcn_mfma_f32_16x16x32_bf16(kf1, qB1, sB, 0, 0, 0);
    if (kt == qtB) {
#pragma unroll
      for (int j = 0; j < 4; ++j)
        if (4 * g + j > c) sB[j] = -1e30f;
    }
    const float pB0 = __expf(sB[0] - 8.f);
    const float pB1 = __expf(sB[1] - 8.f);
    const float pB2 = __expf(sB[2] - 8.f);
    const float pB3 = __expf(sB[3] - 8.f);
    lB += (pB0 + pB1) + (pB2 + pB3);
    bh4 pfB = { f2bf(pB0), f2bf(pB1), f2bf(pB2), f2bf(pB3) };
    oB[0] = __builtin_amdgcn_mfma_f32_16x16x16bf16_1k(vf0, pfB, oB[0], 0, 0, 0);
    oB[1] = __builtin_amdgcn_mfma_f32_16x16x16bf16_1k(vf1, pfB, oB[1], 0, 0, 0);
    oB[2] = __builtin_amdgcn_mfma_f32_16x16x16bf16_1k(vf2, pfB, oB[2], 0, 0, 0);
    oB[3] = __builtin_amdgcn_mfma_f32_16x16x16bf16_1k(vf3, pfB, oB[3], 0, 0, 0);

    if (kt <= qtA) {                          // wave-uniform
      fx4 sA = {0.f, 0.f, 0.f, 0.f};
      sA = __builtin_amdgcn_mfma_f32_16x16x32_bf16(kf0, qA0, sA, 0, 0, 0);
      sA = __builtin_amdgcn_mfma_f32_16x16x32_bf16(kf1, qA1, sA, 0, 0, 0);
      if (kt == qtA) {
#pragma unroll
        for (int j = 0; j < 4; ++j)
          if (4 * g + j > c) sA[j] = -1e30f;
      }
      const float pA0 = __expf(sA[0] - 8.f);
      const float pA1 = __expf(sA[1] - 8.f);
      const float pA2 = __expf(sA[2] - 8.f);
      const float pA3 = __expf(sA[3] - 8.f);
      lA += (pA0 + pA1) + (pA2 + pA3);
      bh4 pfA = { f2bf(pA0), f2bf(pA1), f2bf(pA2), f2bf(pA3) };
      oA[0] = __builtin_amdgcn_mfma_f32_16x16x16bf16_1k(vf0, pfA, oA[0], 0, 0, 0);
      oA[1] = __builtin_amdgcn_mfma_f32_16x16x16bf16_1k(vf1, pfA, oA[1], 0, 0, 0);
      oA[2] = __builtin_amdgcn_mfma_f32_16x16x16bf16_1k(vf2, pfA, oA[2], 0, 0, 0);
      oA[3] = __builtin_amdgcn_mfma_f32_16x16x16bf16_1k(vf3, pfA, oA[3], 0, 0, 0);
    }
  }

  // ---- merge A (linear sum), then merge B, reusing sO/sL ----
#pragma unroll
  for (int mm = 0; mm < 4; ++mm)
    *(fx4*)&sO[w][c][16 * mm + 4 * g] = oA[mm];
  lA += __shfl_xor(lA, 16, 64);
  lA += __shfl_xor(lA, 32, 64);
  if (g == 0) sL[w][c] = lA;
  __syncthreads();
  if (w < 4) {
    const int r = tid >> 4;
    const int cg4 = (tid & 15) * 4;
    fx4 a = {0.f, 0.f, 0.f, 0.f};
    float L = 0.f;
#pragma unroll
    for (int i = 0; i < 8; ++i) { a += *(const fx4*)&sO[i][r][cg4]; L += sL[i][r]; }
    fx4 res = a * (1.0f / L);
    *(fx4*)(out + ((size_t)(b * S_ + qtA * 16 + r)) * HD_ + cg4) = res;
  }
  __syncthreads();
#pragma unroll
  for (int mm = 0; mm < 4; ++mm)
    *(fx4*)&sO[w][c][16 * mm + 4 * g] = oB[mm];
  lB += __shfl_xor(lB, 16, 64);
  lB += __shfl_xor(lB, 32, 64);
  if (g == 0) sL[w][c] = lB;
  __syncthreads();
  if (w < 4) {
    const int r = tid >> 4;
    const int cg4 = (tid & 15) * 4;
    fx4 a = {0.f, 0.f, 0.f, 0.f};
    float L = 0.f;
#pragma unroll
    for (int i = 0; i < 8; ++i) { a += *(const fx4*)&sO[i][r][cg4]; L += sL[i][r]; }
    fx4 res = a * (1.0f / L);
    *(fx4*)(out + ((size_t)(b * S_ + qtB * 16 + r)) * HD_ + cg4) = res;
  }
}

extern "C" void kernel_launch(void* const* d_in, const int* in_sizes, int n_in,
                              void* d_out, int out_size, void* d_ws, size_t ws_size,
                              hipStream_t stream) {
  const float* x  = (const float*)d_in[0];
  const float* wk = (const float*)d_in[1];
  const float* wq = (const float*)d_in[2];
  const float* wv = (const float*)d_in[3];
  float* out = (float*)d_out;
  char* ws = (char*)d_ws;
  short* wc  = (short*)(ws);                         // 384 KB
  short* kfr = (short*)(ws + 393216);                // 2 MB
  short* qfr = (short*)(ws + 2490368);               // 2 MB
  short* vfr = (short*)(ws + 4587520);               // 2 MB (total 6.5 MB)

  castw_k<<<dim3(96), dim3(256), 0, stream>>>(wk, wq, wv, wc);
  qkv_gemm<<<dim3(256), dim3(512), 0, stream>>>(x, wc, kfr, qfr, vfr);
  attn_fused3<<<dim3(512), dim3(512), 0, stream>>>(qfr, kfr, vfr, out);
}